// Round 3
// baseline (352.482 us; speedup 1.0000x reference)
//
#include <hip/hip_runtime.h>
#include <hip/hip_bf16.h>

// Problem constants
#define T_ 32
#define N_ 16
#define C_ 64
#define L_ 64
#define H_ 128
#define G3 384
#define TOT 323

// ws layout (float offsets)
#define OFF_XF 0
#define OFF_XB 393216
#define OFF_XG 786432
#define OFF_Q  983040
#define OFF_V  1048576
#define OFF_HS 1049088
// Kmat (bf16) byte offset: (OFF_HS + 65536)*4
#define KM_OFF 4458496

typedef __attribute__((ext_vector_type(8))) short s16x8;
typedef __attribute__((ext_vector_type(4))) float fx4;

__device__ __forceinline__ unsigned short f2bf(float f) {
  unsigned u = __builtin_bit_cast(unsigned, f);
  unsigned r = (u + 0x7FFFu + ((u >> 16) & 1u)) >> 16;
  return (unsigned short)r;
}
__device__ __forceinline__ float bf2f(unsigned short u) {
  unsigned v = ((unsigned)u) << 16;
  return __builtin_bit_cast(float, v);
}
__device__ __forceinline__ float sigm(float x) {
  return __builtin_amdgcn_rcpf(1.f + __expf(-x));
}
__device__ __forceinline__ float tanh_(float x) {
  return 1.f - 2.f * __builtin_amdgcn_rcpf(__expf(2.f * x) + 1.f);
}

// ---------------------------------------------------------------------------
// pre: blocks [0,128): Xf/Xb = gi @ Wih_d.T + bih_d   (l = bid>>1, d = bid&1)
//      blocks [128,160): xg[t] = aemb[a_prev[t]] @ gc_Wih.T + gc_bih
//      blocks [160,672): per-(t,n) q_all / v_all MLPs (fp32)
// ---------------------------------------------------------------------------
__global__ __launch_bounds__(384) void pre_kernel(
    const float* __restrict__ cond, const int* __restrict__ lines,
    const int* __restrict__ given_a, const float* __restrict__ hx,
    const float* __restrict__ emb, const float* __restrict__ aemb,
    const float* __restrict__ Wih_f, const float* __restrict__ bih_f,
    const float* __restrict__ Wih_b, const float* __restrict__ bih_b,
    const float* __restrict__ gc_Wih, const float* __restrict__ gc_bih,
    const float* __restrict__ f_W0, const float* __restrict__ f_b0,
    const float* __restrict__ f_W1, const float* __restrict__ f_b1,
    const float* __restrict__ f_W2, const float* __restrict__ f_b2,
    const float* __restrict__ c_W0, const float* __restrict__ c_b0,
    const float* __restrict__ c_W1, const float* __restrict__ c_b1,
    const float* __restrict__ c_W2, const float* __restrict__ c_b2,
    float* __restrict__ wsf)
{
  __shared__ __align__(16) float xs[2048];
  const int bid = blockIdx.x, tid = threadIdx.x;

  if (bid < 160) {
    const float* W;
    const float* bias;
    float* outp;
    if (bid < 128) {
      int l = bid >> 1, d = bid & 1;
      for (int idx = tid; idx < 2048; idx += 384) {
        int n = idx >> 7, k = idx & 127;
        int e = lines[n * L_ + l];               // lines_obs[0][n][l]
        xs[idx] = emb[e * H_ + k];
      }
      W = d ? Wih_b : Wih_f;
      bias = d ? bih_b : bih_f;
      outp = wsf + (d ? OFF_XB : OFF_XF) + l * (N_ * G3);
    } else {
      int t = bid - 128;
      for (int idx = tid; idx < 2048; idx += 384) {
        int n = idx >> 7, k = idx & 127;
        int ap = (t == 0) ? (int)hx[n * TOT] : given_a[(t - 1) * N_ + n];
        xs[idx] = aemb[ap * H_ + k];
      }
      W = gc_Wih; bias = gc_bih;
      outp = wsf + OFF_XG + t * (N_ * G3);
    }
    __syncthreads();
    const int c = tid;  // 0..383 = output gate column
    float acc[16];
    float b = bias[c];
    #pragma unroll
    for (int n = 0; n < 16; ++n) acc[n] = b;
    const float4* wr = (const float4*)(W + c * H_);
    #pragma unroll 4
    for (int k4 = 0; k4 < 32; ++k4) {
      float4 w = wr[k4];
      #pragma unroll
      for (int n = 0; n < 16; ++n) {
        float4 x = ((const float4*)(xs + n * H_))[k4];
        acc[n] += w.x * x.x + w.y * x.y + w.z * x.z + w.w * x.w;
      }
    }
    #pragma unroll
    for (int n = 0; n < 16; ++n) outp[n * G3 + c] = acc[n];
  } else {
    // per-(t,n) MLPs
    int tn = bid - 160;
    float* x0 = xs;
    float* x1 = xs + 256;
    float* x2 = xs + 512;
    const int c = tid;
    // q path: relu(relu(relu(cond@f_W0+b)@f_W1+b)@f_W2+b)
    if (c < 64) x0[c] = cond[tn * C_ + c];
    __syncthreads();
    if (c < 128) {
      float s = f_b0[c];
      #pragma unroll 8
      for (int k = 0; k < 64; ++k) s += x0[k] * f_W0[k * H_ + c];
      x1[c] = fmaxf(s, 0.f);
    }
    __syncthreads();
    if (c < 128) {
      float s = f_b1[c];
      #pragma unroll 8
      for (int k = 0; k < 128; ++k) s += x1[k] * f_W1[k * H_ + c];
      x2[c] = fmaxf(s, 0.f);
    }
    __syncthreads();
    if (c < 128) {
      float s = f_b2[c];
      #pragma unroll 8
      for (int k = 0; k < 128; ++k) s += x2[k] * f_W2[k * H_ + c];
      wsf[OFF_Q + tn * H_ + c] = fmaxf(s, 0.f);
    }
    __syncthreads();
    // v path: relu(relu([cond,lines]@c_W0+b)@c_W1+b)@c_W2+b
    if (c < 64) {
      x0[c] = cond[tn * C_ + c];
      x0[64 + c] = (float)lines[tn * L_ + c];
    }
    __syncthreads();
    if (c < 128) {
      float s = c_b0[c];
      #pragma unroll 8
      for (int k = 0; k < 128; ++k) s += x0[k] * c_W0[k * H_ + c];
      x1[c] = fmaxf(s, 0.f);
    }
    __syncthreads();
    if (c < 128) {
      float s = c_b1[c];
      #pragma unroll 8
      for (int k = 0; k < 128; ++k) s += x1[k] * c_W1[k * H_ + c];
      x2[c] = fmaxf(s, 0.f);
    }
    __syncthreads();
    if (c < 128) x0[c] = x2[c] * c_W2[c];
    __syncthreads();
    if (c == 0) {
      float s = c_b2[0];
      for (int k = 0; k < 128; ++k) s += x0[k];
      wsf[OFF_V + tn] = s;
    }
  }
}

// ---------------------------------------------------------------------------
// mid: blocks [0,128): one (roll i, dir d) GRU chain. 8 waves; wave w owns
//   gate columns [16w,16w+16) of r/z/n. Whh fragments live in registers for
//   all 64 steps; h is bf16 in XOR-swizzled LDS (double-buffered).
//      blocks [128,144): gc-GRU chain, one per batch row n.
// ---------------------------------------------------------------------------
__global__ __launch_bounds__(512) void mid_kernel(
    const float* __restrict__ Whh_f, const float* __restrict__ Whh_b,
    const float* __restrict__ bhh_f, const float* __restrict__ bhh_b,
    const float* __restrict__ gc_Whh, const float* __restrict__ gc_bhh,
    const float* __restrict__ hx,
    float* __restrict__ wsf, unsigned short* __restrict__ Km)
{
  __shared__ __align__(16) unsigned short hls[4096];  // 8KB: 2 x [16][128] bf16
  const int bid = blockIdx.x, tid = threadIdx.x;

  if (bid < 128) {
    const int i = bid >> 1, d = bid & 1;
    const float* Whh = d ? Whh_b : Whh_f;
    const float* bhh = d ? bhh_b : bhh_f;
    const float* Xd = wsf + (d ? OFF_XB : OFF_XF);
    const int w = tid >> 6, lane = tid & 63;
    const int col16 = lane & 15, krow = lane >> 4;
    const int bq = krow * 4;          // batch-row base of this lane's D rows
    const int cc = w * 16 + col16;    // h column [0,128)

    for (int idx = tid; idx < 4096; idx += 512) hls[idx] = 0;

    // Preload B fragments (Whh.T tiles) into registers, bf16
    s16x8 Bf[3][4];
    float bias[3];
    int colg[3];
    #pragma unroll
    for (int g = 0; g < 3; ++g) {
      int cg = (g * 8 + w) * 16 + col16;   // gate column in [0,384)
      colg[g] = cg;
      bias[g] = bhh[cg];
      #pragma unroll
      for (int kb = 0; kb < 4; ++kb) {
        const float* src = Whh + cg * H_ + kb * 32 + krow * 8;
        float4 aa = *(const float4*)(src);
        float4 bb = *(const float4*)(src + 4);
        s16x8 s;
        s[0] = (short)f2bf(aa.x); s[1] = (short)f2bf(aa.y);
        s[2] = (short)f2bf(aa.z); s[3] = (short)f2bf(aa.w);
        s[4] = (short)f2bf(bb.x); s[5] = (short)f2bf(bb.y);
        s[6] = (short)f2bf(bb.z); s[7] = (short)f2bf(bb.w);
        Bf[g][kb] = s;
      }
    }
    float hreg[4] = {0.f, 0.f, 0.f, 0.f};
    char* lbase = (char*)hls;
    __syncthreads();

    int p = 0;
    #pragma unroll 1
    for (int s = 0; s < 64; ++s) {
      const int jj = d ? (63 - s) : s;
      const int lx = (jj - i) & 63;
      // x-parts (bih already folded in by pre)
      float xp[3][4];
      #pragma unroll
      for (int g = 0; g < 3; ++g)
        #pragma unroll
        for (int r = 0; r < 4; ++r)
          xp[g][r] = Xd[(lx * N_ + bq + r) * G3 + colg[g]];
      // A fragments from swizzled LDS: row = lane&15
      s16x8 Af[4];
      {
        const int ra = col16;
        #pragma unroll
        for (int kb = 0; kb < 4; ++kb) {
          int ab = ((ra * 256 + kb * 64 + krow * 16) ^ ((ra & 7) << 4));
          Af[kb] = *(const s16x8*)(lbase + p * 4096 + ab);
        }
      }
      fx4 acc[3];
      #pragma unroll
      for (int g = 0; g < 3; ++g) {
        fx4 a;
        a[0] = bias[g]; a[1] = bias[g]; a[2] = bias[g]; a[3] = bias[g];
        #pragma unroll
        for (int kb = 0; kb < 4; ++kb)
          a = __builtin_amdgcn_mfma_f32_16x16x32_bf16(Af[kb], Bf[g][kb], a, 0, 0, 0);
        acc[g] = a;
      }
      // gates + h update + stores
      char* wbb = lbase + (p ^ 1) * 4096;
      #pragma unroll
      for (int r = 0; r < 4; ++r) {
        int b = bq + r;
        float rr = sigm(xp[0][r] + acc[0][r]);
        float zz = sigm(xp[1][r] + acc[1][r]);
        float nn = tanh_(xp[2][r] + rr * acc[2][r]);
        float hn = nn + zz * (hreg[r] - nn);
        hreg[r] = hn;
        unsigned short u = f2bf(hn);
        int wb = ((b * 256 + cc * 2) ^ ((b & 7) << 4));
        *(unsigned short*)(wbb + wb) = u;
        Km[((b * 64 + i) * 128 + (2 * jj + d)) * 128 + cc] = u;
      }
      __syncthreads();
      p ^= 1;
    }
  } else {
    // gc-GRU chain for batch row n
    const int n = bid - 128;
    float* hcur = (float*)hls;         // 128 f32
    float* gh = ((float*)hls) + 128;   // 384 f32
    if (tid < 128) hcur[tid] = hx[n * TOT + 3 + tid];
    __syncthreads();
    #pragma unroll 1
    for (int t = 0; t < 32; ++t) {
      if (tid < 384) {
        float s = gc_bhh[tid];
        const float4* wr = (const float4*)(gc_Whh + tid * H_);
        const float4* hv = (const float4*)hcur;
        #pragma unroll 8
        for (int k4 = 0; k4 < 32; ++k4) {
          float4 w = wr[k4];
          float4 h = hv[k4];
          s += w.x * h.x + w.y * h.y + w.z * h.z + w.w * h.w;
        }
        gh[tid] = s;
      }
      __syncthreads();
      if (tid < 128) {
        const float* xgp = wsf + OFF_XG + (t * N_ + n) * G3;
        float rr = sigm(xgp[tid] + gh[tid]);
        float zz = sigm(xgp[128 + tid] + gh[128 + tid]);
        float nn = tanh_(xgp[256 + tid] + rr * gh[256 + tid]);
        float hn = nn + zz * (hcur[tid] - nn);
        hcur[tid] = hn;
        wsf[OFF_HS + (t * N_ + n) * H_ + tid] = hn;
      }
      __syncthreads();
    }
  }
}

// ---------------------------------------------------------------------------
// post: one block per (t,n). a-MLP + p softmax, K-tile k.q + a softmax,
// assemble all 323 output columns (+ t==31 tail copy). OUTPUT IS FLOAT32.
// ---------------------------------------------------------------------------
__global__ __launch_bounds__(128) void post_kernel(
    const int* __restrict__ given_a, const int* __restrict__ given_p,
    const float* __restrict__ hx,
    const float* __restrict__ a_W0, const float* __restrict__ a_b0,
    const float* __restrict__ a_W1, const float* __restrict__ a_b1,
    const float* __restrict__ a_Wc, const float* __restrict__ a_bc,
    const float* __restrict__ wsf, const unsigned short* __restrict__ Km,
    float* __restrict__ out)
{
  __shared__ __align__(16) unsigned short ktile[16384];  // 32KB bf16, swizzled
  __shared__ float xa[128], xb2[128], qv[128], red[4];
  const int tn = blockIdx.x, t = tn >> 4, n = tn & 15;
  const int c = threadIdx.x;
  const int lane = c & 63, wid = c >> 6;

  // stage K[n][pt] tile, coalesced global -> swizzled LDS
  {
    int pt = given_p[tn];
    const s16x8* src = (const s16x8*)(Km + (n * 64 + pt) * 16384);
    #pragma unroll
    for (int it = 0; it < 16; ++it) {
      int chunk = it * 128 + c;
      s16x8 v = src[chunk];
      int byte = chunk * 16;
      int row = byte >> 8;
      *(s16x8*)((char*)ktile + (byte ^ ((row & 7) << 4))) = v;
    }
  }
  xa[c] = wsf[OFF_HS + tn * H_ + c];
  qv[c] = wsf[OFF_Q + tn * H_ + c];
  __syncthreads();
  // a-MLP
  float s = a_b0[c];
  #pragma unroll 8
  for (int k = 0; k < 128; ++k) s += xa[k] * a_W0[k * H_ + c];
  xb2[c] = fmaxf(s, 0.f);
  __syncthreads();
  s = a_b1[c];
  #pragma unroll 8
  for (int k = 0; k < 128; ++k) s += xb2[k] * a_W1[k * H_ + c];
  float x2v = fmaxf(s, 0.f);
  __syncthreads();
  xa[c] = x2v;
  __syncthreads();
  // a logits: k.q from swizzled LDS tile
  float al = 0.f;
  #pragma unroll
  for (int k8 = 0; k8 < 16; ++k8) {
    int byte = c * 256 + k8 * 16;
    s16x8 kv = *(const s16x8*)((const char*)ktile + (byte ^ ((c & 7) << 4)));
    #pragma unroll
    for (int j = 0; j < 8; ++j)
      al += bf2f((unsigned short)kv[j]) * qv[k8 * 8 + j];
  }
  // p logits (wave 0 only: 64 columns)
  float pl = 0.f;
  if (wid == 0) {
    float s2 = a_bc[lane];
    #pragma unroll 8
    for (int k = 0; k < 128; ++k) s2 += xa[k] * a_Wc[k * 64 + lane];
    pl = s2;
  }
  // a softmax over 128 (two waves + LDS combine)
  float m = al;
  #pragma unroll
  for (int off = 32; off; off >>= 1) m = fmaxf(m, __shfl_xor(m, off));
  if (lane == 0) red[wid] = m;
  __syncthreads();
  m = fmaxf(red[0], red[1]);
  float e = __expf(al - m);
  float ssum = e;
  #pragma unroll
  for (int off = 32; off; off >>= 1) ssum += __shfl_xor(ssum, off);
  if (lane == 0) red[2 + wid] = ssum;
  __syncthreads();
  float ap = e * __builtin_amdgcn_rcpf(red[2] + red[3]);

  const int obase = tn * TOT;
  const bool tail = (t == 31);
  const int tbase = 512 * TOT + n * TOT;
  // a_probs -> cols 131..258
  out[obase + 131 + c] = ap;
  if (tail) out[tbase + 131 + c] = ap;
  // h_rep -> cols 3..130
  {
    float hv = hx[n * TOT + 3 + c];
    out[obase + 3 + c] = hv;
    if (tail) out[tbase + 3 + c] = hv;
  }
  // p_probs -> cols 259..322 (wave 0)
  if (wid == 0) {
    float pm = pl;
    #pragma unroll
    for (int off = 32; off; off >>= 1) pm = fmaxf(pm, __shfl_xor(pm, off));
    float pe = __expf(pl - pm);
    float ps = pe;
    #pragma unroll
    for (int off = 32; off; off >>= 1) ps += __shfl_xor(ps, off);
    float pp = pe * __builtin_amdgcn_rcpf(ps);
    out[obase + 259 + lane] = pp;
    if (tail) out[tbase + 259 + lane] = pp;
  }
  if (c == 0) {
    float u0 = (float)given_a[tn];
    float u1 = (float)given_p[tn];
    float u2 = wsf[OFF_V + tn];
    out[obase + 0] = u0; out[obase + 1] = u1; out[obase + 2] = u2;
    if (tail) { out[tbase + 0] = u0; out[tbase + 1] = u1; out[tbase + 2] = u2; }
  }
}

extern "C" void kernel_launch(void* const* d_in, const int* in_sizes, int n_in,
                              void* d_out, int out_size, void* d_ws, size_t ws_size,
                              hipStream_t stream) {
  const float* cond  = (const float*)d_in[0];
  const int*   lines = (const int*)d_in[1];
  const int*   ga    = (const int*)d_in[2];
  const int*   gp    = (const int*)d_in[3];
  const float* hx    = (const float*)d_in[4];
  const float* emb   = (const float*)d_in[5];
  const float* aemb  = (const float*)d_in[6];
  const float* Wih_f = (const float*)d_in[7];
  const float* Whh_f = (const float*)d_in[8];
  const float* Wih_b = (const float*)d_in[9];
  const float* Whh_b = (const float*)d_in[10];
  const float* gcWih = (const float*)d_in[11];
  const float* gcWhh = (const float*)d_in[12];
  const float* bih_f = (const float*)d_in[13];
  const float* bhh_f = (const float*)d_in[14];
  const float* bih_b = (const float*)d_in[15];
  const float* bhh_b = (const float*)d_in[16];
  const float* gcbih = (const float*)d_in[17];
  const float* gcbhh = (const float*)d_in[18];
  const float* f_W0 = (const float*)d_in[19]; const float* f_b0 = (const float*)d_in[20];
  const float* f_W1 = (const float*)d_in[21]; const float* f_b1 = (const float*)d_in[22];
  const float* f_W2 = (const float*)d_in[23]; const float* f_b2 = (const float*)d_in[24];
  const float* c_W0 = (const float*)d_in[25]; const float* c_b0 = (const float*)d_in[26];
  const float* c_W1 = (const float*)d_in[27]; const float* c_b1 = (const float*)d_in[28];
  const float* c_W2 = (const float*)d_in[29]; const float* c_b2 = (const float*)d_in[30];
  const float* a_W0 = (const float*)d_in[31]; const float* a_b0 = (const float*)d_in[32];
  const float* a_W1 = (const float*)d_in[33]; const float* a_b1 = (const float*)d_in[34];
  const float* a_Wc = (const float*)d_in[35]; const float* a_bc = (const float*)d_in[36];

  float* wsf = (float*)d_ws;
  unsigned short* Km = (unsigned short*)((char*)d_ws + KM_OFF);
  float* out = (float*)d_out;

  pre_kernel<<<672, 384, 0, stream>>>(cond, lines, ga, hx, emb, aemb,
      Wih_f, bih_f, Wih_b, bih_b, gcWih, gcbih,
      f_W0, f_b0, f_W1, f_b1, f_W2, f_b2,
      c_W0, c_b0, c_W1, c_b1, c_W2, c_b2, wsf);
  mid_kernel<<<144, 512, 0, stream>>>(Whh_f, Whh_b, bhh_f, bhh_b,
      gcWhh, gcbhh, hx, wsf, Km);
  post_kernel<<<512, 128, 0, stream>>>(ga, gp, hx,
      a_W0, a_b0, a_W1, a_b1, a_Wc, a_bc, wsf, Km, out);
}

// Round 5
// 233.847 us; speedup vs baseline: 1.5073x; 1.5073x over previous
//
#include <hip/hip_runtime.h>
#include <hip/hip_bf16.h>

// Problem constants
#define T_ 32
#define N_ 16
#define C_ 64
#define L_ 64
#define H_ 128
#define G3 384
#define TOT 323

// ws layout (float offsets)
#define OFF_XF 0
#define OFF_XB 393216
#define OFF_XG 786432
#define OFF_Q  983040
#define OFF_V  1048576
#define OFF_HS 1049088
// Kmat (bf16) byte offset: (OFF_HS + 65536)*4
#define KM_OFF 4458496

typedef __attribute__((ext_vector_type(8))) short s16x8;
typedef __attribute__((ext_vector_type(4))) float fx4;

__device__ __forceinline__ unsigned short f2bf(float f) {
  unsigned u = __builtin_bit_cast(unsigned, f);
  unsigned r = (u + 0x7FFFu + ((u >> 16) & 1u)) >> 16;
  return (unsigned short)r;
}
__device__ __forceinline__ float bf2f(unsigned short u) {
  unsigned v = ((unsigned)u) << 16;
  return __builtin_bit_cast(float, v);
}
__device__ __forceinline__ float sigm(float x) {
  return __builtin_amdgcn_rcpf(1.f + __expf(-x));
}
__device__ __forceinline__ float tanh_(float x) {
  return 1.f - 2.f * __builtin_amdgcn_rcpf(__expf(2.f * x) + 1.f);
}

// ---------------------------------------------------------------------------
// pre: blocks [0,128): Xf/Xb = gi @ Wih_d.T + bih_d   (l = bid>>1, d = bid&1)
//      blocks [128,160): xg[t] = aemb[a_prev[t]] @ gc_Wih.T + gc_bih
//      blocks [160,672): per-(t,n) q_all / v_all MLPs (fp32)
// ---------------------------------------------------------------------------
__global__ __launch_bounds__(384) void pre_kernel(
    const float* __restrict__ cond, const int* __restrict__ lines,
    const int* __restrict__ given_a, const float* __restrict__ hx,
    const float* __restrict__ emb, const float* __restrict__ aemb,
    const float* __restrict__ Wih_f, const float* __restrict__ bih_f,
    const float* __restrict__ Wih_b, const float* __restrict__ bih_b,
    const float* __restrict__ gc_Wih, const float* __restrict__ gc_bih,
    const float* __restrict__ f_W0, const float* __restrict__ f_b0,
    const float* __restrict__ f_W1, const float* __restrict__ f_b1,
    const float* __restrict__ f_W2, const float* __restrict__ f_b2,
    const float* __restrict__ c_W0, const float* __restrict__ c_b0,
    const float* __restrict__ c_W1, const float* __restrict__ c_b1,
    const float* __restrict__ c_W2, const float* __restrict__ c_b2,
    float* __restrict__ wsf)
{
  __shared__ __align__(16) float xs[2048];
  const int bid = blockIdx.x, tid = threadIdx.x;

  if (bid < 160) {
    const float* W;
    const float* bias;
    float* outp;
    if (bid < 128) {
      int l = bid >> 1, d = bid & 1;
      for (int idx = tid; idx < 2048; idx += 384) {
        int n = idx >> 7, k = idx & 127;
        int e = lines[n * L_ + l];               // lines_obs[0][n][l]
        xs[idx] = emb[e * H_ + k];
      }
      W = d ? Wih_b : Wih_f;
      bias = d ? bih_b : bih_f;
      outp = wsf + (d ? OFF_XB : OFF_XF) + l * (N_ * G3);
    } else {
      int t = bid - 128;
      for (int idx = tid; idx < 2048; idx += 384) {
        int n = idx >> 7, k = idx & 127;
        int ap = (t == 0) ? (int)hx[n * TOT] : given_a[(t - 1) * N_ + n];
        xs[idx] = aemb[ap * H_ + k];
      }
      W = gc_Wih; bias = gc_bih;
      outp = wsf + OFF_XG + t * (N_ * G3);
    }
    __syncthreads();
    const int c = tid;  // 0..383 = output gate column
    float acc[16];
    float b = bias[c];
    #pragma unroll
    for (int n = 0; n < 16; ++n) acc[n] = b;
    const float4* wr = (const float4*)(W + c * H_);
    #pragma unroll 4
    for (int k4 = 0; k4 < 32; ++k4) {
      float4 w = wr[k4];
      #pragma unroll
      for (int n = 0; n < 16; ++n) {
        float4 x = ((const float4*)(xs + n * H_))[k4];
        acc[n] += w.x * x.x + w.y * x.y + w.z * x.z + w.w * x.w;
      }
    }
    #pragma unroll
    for (int n = 0; n < 16; ++n) outp[n * G3 + c] = acc[n];
  } else {
    // per-(t,n) MLPs
    int tn = bid - 160;
    float* x0 = xs;
    float* x1 = xs + 256;
    float* x2 = xs + 512;
    const int c = tid;
    // q path: relu(relu(relu(cond@f_W0+b)@f_W1+b)@f_W2+b)
    if (c < 64) x0[c] = cond[tn * C_ + c];
    __syncthreads();
    if (c < 128) {
      float s = f_b0[c];
      #pragma unroll 8
      for (int k = 0; k < 64; ++k) s += x0[k] * f_W0[k * H_ + c];
      x1[c] = fmaxf(s, 0.f);
    }
    __syncthreads();
    if (c < 128) {
      float s = f_b1[c];
      #pragma unroll 8
      for (int k = 0; k < 128; ++k) s += x1[k] * f_W1[k * H_ + c];
      x2[c] = fmaxf(s, 0.f);
    }
    __syncthreads();
    if (c < 128) {
      float s = f_b2[c];
      #pragma unroll 8
      for (int k = 0; k < 128; ++k) s += x2[k] * f_W2[k * H_ + c];
      wsf[OFF_Q + tn * H_ + c] = fmaxf(s, 0.f);
    }
    __syncthreads();
    // v path: relu(relu([cond,lines]@c_W0+b)@c_W1+b)@c_W2+b
    if (c < 64) {
      x0[c] = cond[tn * C_ + c];
      x0[64 + c] = (float)lines[tn * L_ + c];
    }
    __syncthreads();
    if (c < 128) {
      float s = c_b0[c];
      #pragma unroll 8
      for (int k = 0; k < 128; ++k) s += x0[k] * c_W0[k * H_ + c];
      x1[c] = fmaxf(s, 0.f);
    }
    __syncthreads();
    if (c < 128) {
      float s = c_b1[c];
      #pragma unroll 8
      for (int k = 0; k < 128; ++k) s += x1[k] * c_W1[k * H_ + c];
      x2[c] = fmaxf(s, 0.f);
    }
    __syncthreads();
    if (c < 128) x0[c] = x2[c] * c_W2[c];
    __syncthreads();
    if (c == 0) {
      float s = c_b2[0];
      for (int k = 0; k < 128; ++k) s += x0[k];
      wsf[OFF_V + tn] = s;
    }
  }
}

// ---------------------------------------------------------------------------
// mid: blocks [0,128): one (roll i, dir d) GRU chain. 8 waves; wave w owns
//   gate columns [16w,16w+16) of r/z/n. Whh fragments live in registers for
//   all 64 steps; h is bf16 in XOR-swizzled LDS (double-buffered).
//   RAW BARRIERS (lgkm-only): Km stores + xp prefetch stay in flight across
//   the step barrier (the __syncthreads vmcnt(0)-drain was 190us -> the stall).
//      blocks [128,144): gc-GRU chain, one per batch row n (Whh in registers).
// ---------------------------------------------------------------------------
__global__ __launch_bounds__(512) void mid_kernel(
    const float* __restrict__ Whh_f, const float* __restrict__ Whh_b,
    const float* __restrict__ bhh_f, const float* __restrict__ bhh_b,
    const float* __restrict__ gc_Whh, const float* __restrict__ gc_bhh,
    const float* __restrict__ hx,
    float* __restrict__ wsf, unsigned short* __restrict__ Km)
{
  __shared__ __align__(16) unsigned short hls[4096];  // 8KB: 2 x [16][128] bf16
  const int bid = blockIdx.x, tid = threadIdx.x;

  if (bid < 128) {
    const int i = bid >> 1, d = bid & 1;
    const float* Whh = d ? Whh_b : Whh_f;
    const float* bhh = d ? bhh_b : bhh_f;
    const float* Xd = wsf + (d ? OFF_XB : OFF_XF);
    const int w = tid >> 6, lane = tid & 63;
    const int col16 = lane & 15, krow = lane >> 4;
    const int bq = krow * 4;          // batch-row base of this lane's D rows
    const int cc = w * 16 + col16;    // h column [0,128)

    for (int idx = tid; idx < 4096; idx += 512) hls[idx] = 0;

    // Preload B fragments (Whh.T tiles) into registers, bf16
    s16x8 Bf[3][4];
    float bias[3];
    int colg[3];
    #pragma unroll
    for (int g = 0; g < 3; ++g) {
      int cg = (g * 8 + w) * 16 + col16;   // gate column in [0,384)
      colg[g] = cg;
      bias[g] = bhh[cg];
      #pragma unroll
      for (int kb = 0; kb < 4; ++kb) {
        const float* src = Whh + cg * H_ + kb * 32 + krow * 8;
        float4 aa = *(const float4*)(src);
        float4 bb = *(const float4*)(src + 4);
        s16x8 s;
        s[0] = (short)f2bf(aa.x); s[1] = (short)f2bf(aa.y);
        s[2] = (short)f2bf(aa.z); s[3] = (short)f2bf(aa.w);
        s[4] = (short)f2bf(bb.x); s[5] = (short)f2bf(bb.y);
        s[6] = (short)f2bf(bb.z); s[7] = (short)f2bf(bb.w);
        Bf[g][kb] = s;
      }
    }
    float hreg[4] = {0.f, 0.f, 0.f, 0.f};
    char* lbase = (char*)hls;
    __syncthreads();

    // prologue: prefetch x-parts for step 0
    float xpc[3][4];
    {
      int jj0 = d ? 63 : 0;
      int lx0 = (jj0 - i) & 63;
      #pragma unroll
      for (int g = 0; g < 3; ++g)
        #pragma unroll
        for (int r = 0; r < 4; ++r)
          xpc[g][r] = Xd[(lx0 * N_ + bq + r) * G3 + colg[g]];
    }

    int p = 0;
    #pragma unroll 1
    for (int s = 0; s < 64; ++s) {
      const int jj = d ? (63 - s) : s;
      // issue prefetch for step s+1 (s=63 issues a harmless valid-range load)
      const int jn = d ? ((62 - s) & 63) : ((s + 1) & 63);
      const int lxn = (jn - i) & 63;
      float xpn[3][4];
      #pragma unroll
      for (int g = 0; g < 3; ++g)
        #pragma unroll
        for (int r = 0; r < 4; ++r)
          xpn[g][r] = Xd[(lxn * N_ + bq + r) * G3 + colg[g]];
      // A fragments from swizzled LDS: row = lane&15
      s16x8 Af[4];
      {
        const int ra = col16;
        #pragma unroll
        for (int kb = 0; kb < 4; ++kb) {
          int ab = ((ra * 256 + kb * 64 + krow * 16) ^ ((ra & 7) << 4));
          Af[kb] = *(const s16x8*)(lbase + p * 4096 + ab);
        }
      }
      fx4 acc[3];
      #pragma unroll
      for (int g = 0; g < 3; ++g) {
        fx4 a;
        a[0] = bias[g]; a[1] = bias[g]; a[2] = bias[g]; a[3] = bias[g];
        #pragma unroll
        for (int kb = 0; kb < 4; ++kb)
          a = __builtin_amdgcn_mfma_f32_16x16x32_bf16(Af[kb], Bf[g][kb], a, 0, 0, 0);
        acc[g] = a;
      }
      // gates + h update + stores
      char* wbb = lbase + (p ^ 1) * 4096;
      #pragma unroll
      for (int r = 0; r < 4; ++r) {
        int b = bq + r;
        float rr = sigm(xpc[0][r] + acc[0][r]);
        float zz = sigm(xpc[1][r] + acc[1][r]);
        float nn = tanh_(xpc[2][r] + rr * acc[2][r]);
        float hn = nn + zz * (hreg[r] - nn);
        hreg[r] = hn;
        unsigned short u = f2bf(hn);
        int wb = ((b * 256 + cc * 2) ^ ((b & 7) << 4));
        *(unsigned short*)(wbb + wb) = u;
        Km[((b * 64 + i) * 128 + (2 * jj + d)) * 128 + cc] = u;
      }
      // raw barrier: only drain LDS ops; Km stores + xp prefetch stay in flight
      asm volatile("s_waitcnt lgkmcnt(0)" ::: "memory");
      __builtin_amdgcn_s_barrier();
      asm volatile("" ::: "memory");
      p ^= 1;
      // rotate prefetched x-parts
      #pragma unroll
      for (int g = 0; g < 3; ++g)
        #pragma unroll
        for (int r = 0; r < 4; ++r)
          xpc[g][r] = xpn[g][r];
    }
  } else {
    // gc-GRU chain for batch row n; gc_Whh row held in registers
    const int n = bid - 128;
    float* hcur = (float*)hls;         // 128 f32
    float* gh = ((float*)hls) + 128;   // 384 f32
    float4 wreg[32];
    float bias_ = 0.f;
    if (tid < 384) {
      const float4* wr = (const float4*)(gc_Whh + tid * H_);
      #pragma unroll
      for (int k4 = 0; k4 < 32; ++k4) wreg[k4] = wr[k4];
      bias_ = gc_bhh[tid];
    }
    if (tid < 128) hcur[tid] = hx[n * TOT + 3 + tid];
    __syncthreads();
    #pragma unroll 1
    for (int t = 0; t < 32; ++t) {
      if (tid < 384) {
        float a0 = bias_, a1 = 0.f, a2 = 0.f, a3 = 0.f;
        const float4* hv = (const float4*)hcur;
        #pragma unroll
        for (int k4 = 0; k4 < 32; k4 += 4) {
          float4 w0 = wreg[k4],     h0 = hv[k4];
          float4 w1 = wreg[k4 + 1], h1 = hv[k4 + 1];
          float4 w2 = wreg[k4 + 2], h2 = hv[k4 + 2];
          float4 w3 = wreg[k4 + 3], h3 = hv[k4 + 3];
          a0 += w0.x * h0.x + w0.y * h0.y + w0.z * h0.z + w0.w * h0.w;
          a1 += w1.x * h1.x + w1.y * h1.y + w1.z * h1.z + w1.w * h1.w;
          a2 += w2.x * h2.x + w2.y * h2.y + w2.z * h2.z + w2.w * h2.w;
          a3 += w3.x * h3.x + w3.y * h3.y + w3.z * h3.z + w3.w * h3.w;
        }
        gh[tid] = (a0 + a1) + (a2 + a3);
      }
      __syncthreads();
      if (tid < 128) {
        const float* xgp = wsf + OFF_XG + (t * N_ + n) * G3;
        float rr = sigm(xgp[tid] + gh[tid]);
        float zz = sigm(xgp[128 + tid] + gh[128 + tid]);
        float nn = tanh_(xgp[256 + tid] + rr * gh[256 + tid]);
        float hn = nn + zz * (hcur[tid] - nn);
        hcur[tid] = hn;
        wsf[OFF_HS + (t * N_ + n) * H_ + tid] = hn;
      }
      __syncthreads();
    }
  }
}

// ---------------------------------------------------------------------------
// post: one block per (t,n). a-MLP + p softmax, K-tile k.q + a softmax,
// assemble all 323 output columns (+ t==31 tail copy). OUTPUT IS FLOAT32.
// ---------------------------------------------------------------------------
__global__ __launch_bounds__(128) void post_kernel(
    const int* __restrict__ given_a, const int* __restrict__ given_p,
    const float* __restrict__ hx,
    const float* __restrict__ a_W0, const float* __restrict__ a_b0,
    const float* __restrict__ a_W1, const float* __restrict__ a_b1,
    const float* __restrict__ a_Wc, const float* __restrict__ a_bc,
    const float* __restrict__ wsf, const unsigned short* __restrict__ Km,
    float* __restrict__ out)
{
  __shared__ __align__(16) unsigned short ktile[16384];  // 32KB bf16, swizzled
  __shared__ float xa[128], xb2[128], qv[128], red[4];
  const int tn = blockIdx.x, t = tn >> 4, n = tn & 15;
  const int c = threadIdx.x;
  const int lane = c & 63, wid = c >> 6;

  // stage K[n][pt] tile, coalesced global -> swizzled LDS
  {
    int pt = given_p[tn];
    const s16x8* src = (const s16x8*)(Km + (n * 64 + pt) * 16384);
    #pragma unroll
    for (int it = 0; it < 16; ++it) {
      int chunk = it * 128 + c;
      s16x8 v = src[chunk];
      int byte = chunk * 16;
      int row = byte >> 8;
      *(s16x8*)((char*)ktile + (byte ^ ((row & 7) << 4))) = v;
    }
  }
  xa[c] = wsf[OFF_HS + tn * H_ + c];
  qv[c] = wsf[OFF_Q + tn * H_ + c];
  __syncthreads();
  // a-MLP
  float s = a_b0[c];
  #pragma unroll 8
  for (int k = 0; k < 128; ++k) s += xa[k] * a_W0[k * H_ + c];
  xb2[c] = fmaxf(s, 0.f);
  __syncthreads();
  s = a_b1[c];
  #pragma unroll 8
  for (int k = 0; k < 128; ++k) s += xb2[k] * a_W1[k * H_ + c];
  float x2v = fmaxf(s, 0.f);
  __syncthreads();
  xa[c] = x2v;
  __syncthreads();
  // a logits: k.q from swizzled LDS tile
  float al = 0.f;
  #pragma unroll
  for (int k8 = 0; k8 < 16; ++k8) {
    int byte = c * 256 + k8 * 16;
    s16x8 kv = *(const s16x8*)((const char*)ktile + (byte ^ ((c & 7) << 4)));
    #pragma unroll
    for (int j = 0; j < 8; ++j)
      al += bf2f((unsigned short)kv[j]) * qv[k8 * 8 + j];
  }
  // p logits (wave 0 only: 64 columns)
  float pl = 0.f;
  if (wid == 0) {
    float s2 = a_bc[lane];
    #pragma unroll 8
    for (int k = 0; k < 128; ++k) s2 += xa[k] * a_Wc[k * 64 + lane];
    pl = s2;
  }
  // a softmax over 128 (two waves + LDS combine)
  float m = al;
  #pragma unroll
  for (int off = 32; off; off >>= 1) m = fmaxf(m, __shfl_xor(m, off));
  if (lane == 0) red[wid] = m;
  __syncthreads();
  m = fmaxf(red[0], red[1]);
  float e = __expf(al - m);
  float ssum = e;
  #pragma unroll
  for (int off = 32; off; off >>= 1) ssum += __shfl_xor(ssum, off);
  if (lane == 0) red[2 + wid] = ssum;
  __syncthreads();
  float ap = e * __builtin_amdgcn_rcpf(red[2] + red[3]);

  const int obase = tn * TOT;
  const bool tail = (t == 31);
  const int tbase = 512 * TOT + n * TOT;
  // a_probs -> cols 131..258
  out[obase + 131 + c] = ap;
  if (tail) out[tbase + 131 + c] = ap;
  // h_rep -> cols 3..130
  {
    float hv = hx[n * TOT + 3 + c];
    out[obase + 3 + c] = hv;
    if (tail) out[tbase + 3 + c] = hv;
  }
  // p_probs -> cols 259..322 (wave 0)
  if (wid == 0) {
    float pm = pl;
    #pragma unroll
    for (int off = 32; off; off >>= 1) pm = fmaxf(pm, __shfl_xor(pm, off));
    float pe = __expf(pl - pm);
    float ps = pe;
    #pragma unroll
    for (int off = 32; off; off >>= 1) ps += __shfl_xor(ps, off);
    float pp = pe * __builtin_amdgcn_rcpf(ps);
    out[obase + 259 + lane] = pp;
    if (tail) out[tbase + 259 + lane] = pp;
  }
  if (c == 0) {
    float u0 = (float)given_a[tn];
    float u1 = (float)given_p[tn];
    float u2 = wsf[OFF_V + tn];
    out[obase + 0] = u0; out[obase + 1] = u1; out[obase + 2] = u2;
    if (tail) { out[tbase + 0] = u0; out[tbase + 1] = u1; out[tbase + 2] = u2; }
  }
}

extern "C" void kernel_launch(void* const* d_in, const int* in_sizes, int n_in,
                              void* d_out, int out_size, void* d_ws, size_t ws_size,
                              hipStream_t stream) {
  const float* cond  = (const float*)d_in[0];
  const int*   lines = (const int*)d_in[1];
  const int*   ga    = (const int*)d_in[2];
  const int*   gp    = (const int*)d_in[3];
  const float* hx    = (const float*)d_in[4];
  const float* emb   = (const float*)d_in[5];
  const float* aemb  = (const float*)d_in[6];
  const float* Wih_f = (const float*)d_in[7];
  const float* Whh_f = (const float*)d_in[8];
  const float* Wih_b = (const float*)d_in[9];
  const float* Whh_b = (const float*)d_in[10];
  const float* gcWih = (const float*)d_in[11];
  const float* gcWhh = (const float*)d_in[12];
  const float* bih_f = (const float*)d_in[13];
  const float* bhh_f = (const float*)d_in[14];
  const float* bih_b = (const float*)d_in[15];
  const float* bhh_b = (const float*)d_in[16];
  const float* gcbih = (const float*)d_in[17];
  const float* gcbhh = (const float*)d_in[18];
  const float* f_W0 = (const float*)d_in[19]; const float* f_b0 = (const float*)d_in[20];
  const float* f_W1 = (const float*)d_in[21]; const float* f_b1 = (const float*)d_in[22];
  const float* f_W2 = (const float*)d_in[23]; const float* f_b2 = (const float*)d_in[24];
  const float* c_W0 = (const float*)d_in[25]; const float* c_b0 = (const float*)d_in[26];
  const float* c_W1 = (const float*)d_in[27]; const float* c_b1 = (const float*)d_in[28];
  const float* c_W2 = (const float*)d_in[29]; const float* c_b2 = (const float*)d_in[30];
  const float* a_W0 = (const float*)d_in[31]; const float* a_b0 = (const float*)d_in[32];
  const float* a_W1 = (const float*)d_in[33]; const float* a_b1 = (const float*)d_in[34];
  const float* a_Wc = (const float*)d_in[35]; const float* a_bc = (const float*)d_in[36];

  float* wsf = (float*)d_ws;
  unsigned short* Km = (unsigned short*)((char*)d_ws + KM_OFF);
  float* out = (float*)d_out;

  pre_kernel<<<672, 384, 0, stream>>>(cond, lines, ga, hx, emb, aemb,
      Wih_f, bih_f, Wih_b, bih_b, gcWih, gcbih,
      f_W0, f_b0, f_W1, f_b1, f_W2, f_b2,
      c_W0, c_b0, c_W1, c_b1, c_W2, c_b2, wsf);
  mid_kernel<<<144, 512, 0, stream>>>(Whh_f, Whh_b, bhh_f, bhh_b,
      gcWhh, gcbhh, hx, wsf, Km);
  post_kernel<<<512, 128, 0, stream>>>(ga, gp, hx,
      a_W0, a_b0, a_W1, a_b1, a_Wc, a_bc, wsf, Km, out);
}